// Round 5
// baseline (254.773 us; speedup 1.0000x reference)
//
#include <hip/hip_runtime.h>
#include <hip/hip_bf16.h>

#define B_  64
#define N_  325
#define T_  24
#define F_  64
#define H_  64
#define E_  2600
#define G_  (B_ * T_)
#define BLK 512
#define NP  336   // padded N stride for as/ad workspace
#define HS  66    // (fallback kernel) h_s row stride in bf16 units

typedef __attribute__((ext_vector_type(8))) short short8;   // 8 bf16 (4 VGPRs)
typedef __attribute__((ext_vector_type(4))) float f32x4;

// ---------------- K0a: per-dst counts -> exclusive offsets ----------------
__global__ __launch_bounds__(512) void k_offsets(const int* __restrict__ ei,
                                                 int* __restrict__ csr_off) {
  __shared__ int cnt[N_];
  const int tid = threadIdx.x;
  for (int i = tid; i < N_; i += BLK) cnt[i] = 0;
  __syncthreads();
  for (int e = tid; e < E_; e += BLK) atomicAdd(&cnt[ei[E_ + e]], 1);
  __syncthreads();
  if (tid <= N_) {
    int off = 0;
    for (int m = 0; m < N_; ++m) off += (m < tid) ? cnt[m] : 0;  // uniform m -> LDS broadcast
    csr_off[tid] = off;
  }
}

// ---------------- K0b: stable scatter of src ids by dst (deterministic) ----------------
__global__ __launch_bounds__(64) void k_scatter(const int* __restrict__ ei,
                                                const int* __restrict__ csr_off,
                                                int* __restrict__ csr_src) {
  __shared__ int dsts[E_];
  const int tid = threadIdx.x;
  for (int i = tid; i < E_; i += 64) dsts[i] = ei[E_ + i];
  __syncthreads();
  const int e = blockIdx.x * 64 + tid;
  if (e >= E_) return;
  const int myd = dsts[e];
  int rank = 0;
#pragma unroll 4
  for (int k = 0; k < e; ++k) rank += (dsts[k] == myd) ? 1 : 0;
  csr_src[csr_off[myd] + rank] = ei[e];  // src id, stable original-edge order
}

// ---------------- K0c: w_s = W^T att_src, w_d = W^T att_dst ----------------
__global__ __launch_bounds__(64) void k_prep(const float* __restrict__ W,
                                             const float* __restrict__ att_src,
                                             const float* __restrict__ att_dst,
                                             float* __restrict__ w_s,
                                             float* __restrict__ w_d) {
  const int k = threadIdx.x;
  float s = 0.f, d = 0.f;
  for (int h = 0; h < H_; ++h) {
    const float w = W[h * F_ + k];
    s += w * att_src[h];
    d += w * att_dst[h];
  }
  w_s[k] = s; w_d[k] = d;
}

__device__ __forceinline__ float bflo(unsigned u) { return __uint_as_float(u << 16); }
__device__ __forceinline__ float bfhi(unsigned u) { return __uint_as_float(u & 0xffff0000u); }

__device__ __forceinline__ unsigned short f2bf(float f) {
  __hip_bfloat16 h = __float2bfloat16(f);
  return *(unsigned short*)&h;
}

__device__ __forceinline__ short8 pack8(float4 u, float4 w) {
  short8 r;
  r[0] = (short)f2bf(u.x); r[1] = (short)f2bf(u.y);
  r[2] = (short)f2bf(u.z); r[3] = (short)f2bf(u.w);
  r[4] = (short)f2bf(w.x); r[5] = (short)f2bf(w.y);
  r[6] = (short)f2bf(w.z); r[7] = (short)f2bf(w.w);
  return r;
}

__device__ __forceinline__ short8 ld8_bf16(const float* p) {
  return pack8(*(const float4*)p, *(const float4*)(p + 4));
}

// GELU via tanh form (max dev from exact ~3e-3, inside budget)
__device__ __forceinline__ float gelu_f(float v) {
  float t = v * (1.5957691216f + 0.0713550903f * (v * v));
  t = fminf(t, 80.0f);
  float e = __expf(t);
  return v * e * __builtin_amdgcn_rcpf(e + 1.0f);
}

// ---------------- K1: h = x @ W^T (bf16 to global) + a_s/a_d, zero LDS ----------------
__global__ __launch_bounds__(512, 4) void k_gemm(
    const float* __restrict__ x, const float* __restrict__ W,
    const float* __restrict__ w_s, const float* __restrict__ w_d,
    unsigned short* __restrict__ h_g, float* __restrict__ as_g,
    float* __restrict__ ad_g) {
  const int g    = blockIdx.x;
  const int bb   = g / T_;
  const int tt   = g % T_;
  const int lane = threadIdx.x & 63;
  const int wv   = threadIdx.x >> 6;
  const int l15  = lane & 15;
  const int l4   = lane >> 4;

  // B fragments: B[k][c] = W[c][k], lane holds col ct*16+l15, k = k0*32 + l4*8 + j
  short8 bf[2][4];
#pragma unroll
  for (int ct = 0; ct < 4; ++ct)
#pragma unroll
    for (int k0 = 0; k0 < 2; ++k0)
      bf[k0][ct] = ld8_bf16(W + (size_t)(ct * 16 + l15) * F_ + k0 * 32 + l4 * 8);

  // per-lane w_s/w_d slices for this lane's k-range
  float wsr[16], wdr[16];
#pragma unroll
  for (int k0 = 0; k0 < 2; ++k0)
#pragma unroll
    for (int j = 0; j < 8; ++j) {
      wsr[k0 * 8 + j] = w_s[k0 * 32 + l4 * 8 + j];
      wdr[k0 * 8 + j] = w_d[k0 * 32 + l4 * 8 + j];
    }

  const float* xg = x + ((size_t)bb * N_ * T_ + tt) * F_;
  unsigned short* hg = h_g + (size_t)g * N_ * H_;

  for (int t = wv; t < 21; t += 8) {
    const int r0 = t * 16;
    int rr = r0 + l15; if (rr > N_ - 1) rr = N_ - 1;   // clamp for partial tile
    const float* xr = xg + (size_t)rr * (T_ * F_);
    const float4 u0 = *(const float4*)(xr + l4 * 8);
    const float4 u1 = *(const float4*)(xr + l4 * 8 + 4);
    const float4 u2 = *(const float4*)(xr + 32 + l4 * 8);
    const float4 u3 = *(const float4*)(xr + 32 + l4 * 8 + 4);

    // attention logits in f32: partial dot over this lane's 16 k-values
    float asv = u0.x*wsr[0] + u0.y*wsr[1] + u0.z*wsr[2] + u0.w*wsr[3]
              + u1.x*wsr[4] + u1.y*wsr[5] + u1.z*wsr[6] + u1.w*wsr[7]
              + u2.x*wsr[8] + u2.y*wsr[9] + u2.z*wsr[10]+ u2.w*wsr[11]
              + u3.x*wsr[12]+ u3.y*wsr[13]+ u3.z*wsr[14]+ u3.w*wsr[15];
    float adv = u0.x*wdr[0] + u0.y*wdr[1] + u0.z*wdr[2] + u0.w*wdr[3]
              + u1.x*wdr[4] + u1.y*wdr[5] + u1.z*wdr[6] + u1.w*wdr[7]
              + u2.x*wdr[8] + u2.y*wdr[9] + u2.z*wdr[10]+ u2.w*wdr[11]
              + u3.x*wdr[12]+ u3.y*wdr[13]+ u3.z*wdr[14]+ u3.w*wdr[15];
    asv += __shfl_xor(asv, 16, 64); asv += __shfl_xor(asv, 32, 64);
    adv += __shfl_xor(adv, 16, 64); adv += __shfl_xor(adv, 32, 64);
    if (l4 == 0 && r0 + l15 < N_) {
      as_g[(size_t)g * NP + r0 + l15] = asv;
      ad_g[(size_t)g * NP + r0 + l15] = adv;
    }

    const short8 a0 = pack8(u0, u1);   // k 0..31
    const short8 a1 = pack8(u2, u3);   // k 32..63
#pragma unroll
    for (int ct = 0; ct < 4; ++ct) {
      f32x4 acc = {0.f, 0.f, 0.f, 0.f};
      acc = __builtin_amdgcn_mfma_f32_16x16x32_bf16(a0, bf[0][ct], acc, 0, 0, 0);
      acc = __builtin_amdgcn_mfma_f32_16x16x32_bf16(a1, bf[1][ct], acc, 0, 0, 0);
      const int col = ct * 16 + l15;                    // C: col = lane&15
#pragma unroll
      for (int j = 0; j < 4; ++j) {                     // C: row = (lane>>4)*4 + j
        const int row = r0 + l4 * 4 + j;
        if (row < N_) hg[row * H_ + col] = f2bf(acc[j]);
      }
    }
  }
}

// ---------------- K2: segment softmax + aggregation + GELU ----------------
__global__ __launch_bounds__(512, 8) void k_attn(
    const unsigned short* __restrict__ h_g, const int* __restrict__ csr_off_g,
    const int* __restrict__ csr_src_g, const float* __restrict__ as_g,
    const float* __restrict__ ad_g, const float* __restrict__ bias,
    float* __restrict__ out) {
  __shared__ float alpha_s[E_];             // 10400 B (unnormalized exp)
  __shared__ unsigned short csrc_s[E_];     //  5200 B
  __shared__ int   coff_s[N_ + 1];          //  1304 B
  __shared__ float as_s[N_], den_s[N_];     //  2600 B   total ~19.5 KB

  const int g    = blockIdx.x;
  const int tid  = threadIdx.x;
  const int lane = tid & 63;
  const int wv   = tid >> 6;

  for (int i = tid; i < E_; i += BLK) csrc_s[i] = (unsigned short)csr_src_g[i];
  for (int i = tid; i <= N_; i += BLK) coff_s[i] = csr_off_g[i];
  if (tid < N_) as_s[tid] = as_g[(size_t)g * NP + tid];
  __syncthreads();

  // segment softmax, thread per dst (N_=325 <= 512: one pass)
  if (tid < N_) {
    const int n = tid;
    const int beg = coff_s[n], end = coff_s[n + 1];
    const float adn = ad_g[(size_t)g * NP + n];
    float mx = -1e30f;
    for (int p = beg; p < end; ++p) {
      float e = as_s[csrc_s[p]] + adn;
      e = fmaxf(e, 0.2f * e);                 // leaky_relu
      alpha_s[p] = e;
      mx = fmaxf(mx, e);
    }
    float den = 0.f;
    for (int p = beg; p < end; ++p) {
      float ex = __expf(alpha_s[p] - mx);
      alpha_s[p] = ex;                        // unnormalized
      den += ex;
    }
    den_s[n] = (end > beg) ? (1.0f / den) : 1.0f;
  }
  __syncthreads();

  // aggregation + GELU: half-wave per dst, h rows gathered from global (L2-hot)
  const int k   = lane & 31;
  const int sub = lane >> 5;
  const float2 bias2 = *(const float2*)(bias + 2 * k);
  const unsigned short* hg = h_g + (size_t)g * N_ * H_;
  for (int n = wv * 2 + sub; n < N_; n += 16) {
    const int beg = coff_s[n], end = coff_s[n + 1];
    float ax = 0.f, ay = 0.f;
    for (int p = beg; p < end; ++p) {
      const float a = alpha_s[p];             // half-wave broadcast
      const int   s = csrc_s[p];
      unsigned hp = *(const unsigned*)(hg + ((size_t)s << 6) + 2 * k);  // 128B contig
      ax += a * bflo(hp);
      ay += a * bfhi(hp);
    }
    const float r = den_s[n];
    float v0 = gelu_f(ax * r + bias2.x);
    float v1 = gelu_f(ay * r + bias2.y);
    *(float2*)&out[((size_t)g * N_ + n) * H_ + 2 * k] = make_float2(v0, v1);
  }
}

// ================= fallback: R4 fused kernel (used if ws too small) =================
__global__ __launch_bounds__(512, 4) void k_gat(
    const float* __restrict__ x, const int* __restrict__ csr_off_g,
    const int* __restrict__ csr_src_g, const float* __restrict__ W,
    const float* __restrict__ att_src, const float* __restrict__ att_dst,
    const float* __restrict__ bias, float* __restrict__ out) {
  __shared__ unsigned short h_s[N_][HS];
  __shared__ float alpha_s[E_];
  __shared__ unsigned short csrc_s[E_];
  __shared__ int   coff_s[N_ + 1];
  __shared__ float as_s[N_], ad_s[N_], den_s[N_];
  __shared__ __align__(8) float atts_s[H_], attd_s[H_];

  const int g    = blockIdx.x;
  const int bb   = g / T_;
  const int tt   = g % T_;
  const int tid  = threadIdx.x;
  const int lane = tid & 63;
  const int wv   = tid >> 6;
  const int l15  = lane & 15;
  const int l4   = lane >> 4;

  for (int i = tid; i < E_; i += BLK) csrc_s[i] = (unsigned short)csr_src_g[i];
  for (int i = tid; i <= N_; i += BLK) coff_s[i] = csr_off_g[i];
  if (tid < H_) { atts_s[tid] = att_src[tid]; attd_s[tid] = att_dst[tid]; }

  short8 bf[2][4];
#pragma unroll
  for (int ct = 0; ct < 4; ++ct)
#pragma unroll
    for (int k0 = 0; k0 < 2; ++k0)
      bf[k0][ct] = ld8_bf16(W + (size_t)(ct * 16 + l15) * F_ + k0 * 32 + l4 * 8);

  const float* xg = x + ((size_t)bb * N_ * T_ + tt) * F_;
  for (int t = wv; t < 21; t += 8) {
    const int r0 = t * 16;
    int rr = r0 + l15; if (rr > N_ - 1) rr = N_ - 1;
    const float* xr = xg + (size_t)rr * (T_ * F_);
    const short8 a0 = ld8_bf16(xr + l4 * 8);
    const short8 a1 = ld8_bf16(xr + 32 + l4 * 8);
#pragma unroll
    for (int ct = 0; ct < 4; ++ct) {
      f32x4 acc = {0.f, 0.f, 0.f, 0.f};
      acc = __builtin_amdgcn_mfma_f32_16x16x32_bf16(a0, bf[0][ct], acc, 0, 0, 0);
      acc = __builtin_amdgcn_mfma_f32_16x16x32_bf16(a1, bf[1][ct], acc, 0, 0, 0);
      const int col = ct * 16 + l15;
#pragma unroll
      for (int j = 0; j < 4; ++j) {
        const int row = r0 + l4 * 4 + j;
        if (row < N_) h_s[row][col] = f2bf(acc[j]);
      }
    }
  }
  __syncthreads();

  for (int n = tid; n < N_; n += BLK) {
    const unsigned* hr = (const unsigned*)&h_s[n][0];
    const float2* at2 = (const float2*)atts_s;
    const float2* ad2 = (const float2*)attd_s;
    float as = 0.f, ad = 0.f;
#pragma unroll
    for (int i = 0; i < 32; ++i) {
      unsigned hp = hr[i];
      float h0 = bflo(hp), h1 = bfhi(hp);
      float2 s2 = at2[i], d2 = ad2[i];
      as += h0 * s2.x + h1 * s2.y;
      ad += h0 * d2.x + h1 * d2.y;
    }
    as_s[n] = as; ad_s[n] = ad;
  }
  __syncthreads();

  for (int n = tid; n < N_; n += BLK) {
    const int beg = coff_s[n], end = coff_s[n + 1];
    const float adn = ad_s[n];
    float mx = -1e30f;
    for (int p = beg; p < end; ++p) {
      float e = as_s[csrc_s[p]] + adn;
      e = fmaxf(e, 0.2f * e);
      alpha_s[p] = e;
      mx = fmaxf(mx, e);
    }
    float den = 0.f;
    for (int p = beg; p < end; ++p) {
      float ex = __expf(alpha_s[p] - mx);
      alpha_s[p] = ex;
      den += ex;
    }
    den_s[n] = (end > beg) ? (1.0f / den) : 1.0f;
  }
  __syncthreads();

  const int k   = lane & 31;
  const int sub = lane >> 5;
  const float2 bias2 = *(const float2*)(bias + 2 * k);
  for (int n = wv * 2 + sub; n < N_; n += 16) {
    const int beg = coff_s[n], end = coff_s[n + 1];
    float ax = 0.f, ay = 0.f;
    for (int p = beg; p < end; ++p) {
      const float a = alpha_s[p];
      const int   s = csrc_s[p];
      unsigned hp = *(const unsigned*)&h_s[s][2 * k];
      ax += a * bflo(hp);
      ay += a * bfhi(hp);
    }
    const float r = den_s[n];
    float v0 = gelu_f(ax * r + bias2.x);
    float v1 = gelu_f(ay * r + bias2.y);
    *(float2*)&out[((size_t)g * N_ + n) * H_ + 2 * k] = make_float2(v0, v1);
  }
}

extern "C" void kernel_launch(void* const* d_in, const int* in_sizes, int n_in,
                              void* d_out, int out_size, void* d_ws, size_t ws_size,
                              hipStream_t stream) {
  (void)in_sizes; (void)n_in; (void)out_size;
  const float* x       = (const float*)d_in[0];
  const int*   ei      = (const int*)d_in[1];
  const float* W       = (const float*)d_in[2];
  const float* att_src = (const float*)d_in[3];
  const float* att_dst = (const float*)d_in[4];
  const float* bias    = (const float*)d_in[5];
  float* out = (float*)d_out;

  char* ws = (char*)d_ws;
  size_t off = 0;
  int* csr_off = (int*)(ws + off); off += (N_ + 1) * sizeof(int);
  int* csr_src = (int*)(ws + off); off += E_ * sizeof(int);
  float* w_s = (float*)(ws + off); off += F_ * sizeof(float);
  float* w_d = (float*)(ws + off); off += F_ * sizeof(float);
  float* as_g = (float*)(ws + off); off += (size_t)G_ * NP * sizeof(float);
  float* ad_g = (float*)(ws + off); off += (size_t)G_ * NP * sizeof(float);
  off = (off + 15) & ~(size_t)15;
  unsigned short* h_g = (unsigned short*)(ws + off);
  off += (size_t)G_ * N_ * H_ * sizeof(unsigned short);

  k_offsets<<<1, BLK, 0, stream>>>(ei, csr_off);
  k_scatter<<<(E_ + 63) / 64, 64, 0, stream>>>(ei, csr_off, csr_src);

  if (off <= ws_size) {
    k_prep<<<1, 64, 0, stream>>>(W, att_src, att_dst, w_s, w_d);
    k_gemm<<<G_, BLK, 0, stream>>>(x, W, w_s, w_d, h_g, as_g, ad_g);
    k_attn<<<G_, BLK, 0, stream>>>(h_g, csr_off, csr_src, as_g, ad_g, bias, out);
  } else {
    k_gat<<<G_, BLK, 0, stream>>>(x, csr_off, csr_src, W, att_src, att_dst, bias, out);
  }
}

// Round 6
// 152.769 us; speedup vs baseline: 1.6677x; 1.6677x over previous
//
#include <hip/hip_runtime.h>
#include <hip/hip_bf16.h>

#define B_  64
#define N_  325
#define T_  24
#define F_  64
#define H_  64
#define E_  2600
#define G_  (B_ * T_)
#define BLK 512

typedef __attribute__((ext_vector_type(8))) short short8;   // 8 bf16 (4 VGPRs)
typedef __attribute__((ext_vector_type(4))) float f32x4;

// ---------------- K0a: per-dst counts -> exclusive offsets ----------------
__global__ __launch_bounds__(512) void k_offsets(const int* __restrict__ ei,
                                                 int* __restrict__ csr_off) {
  __shared__ int cnt[N_];
  const int tid = threadIdx.x;
  for (int i = tid; i < N_; i += BLK) cnt[i] = 0;
  __syncthreads();
  for (int e = tid; e < E_; e += BLK) atomicAdd(&cnt[ei[E_ + e]], 1);
  __syncthreads();
  if (tid <= N_) {
    int off = 0;
    for (int m = 0; m < N_; ++m) off += (m < tid) ? cnt[m] : 0;  // uniform m -> LDS broadcast
    csr_off[tid] = off;
  }
}

// ---------------- K0b: stable scatter of src ids by dst (deterministic) ----------------
__global__ __launch_bounds__(64) void k_scatter(const int* __restrict__ ei,
                                                const int* __restrict__ csr_off,
                                                int* __restrict__ csr_src) {
  __shared__ int dsts[E_];
  const int tid = threadIdx.x;
  for (int i = tid; i < E_; i += 64) dsts[i] = ei[E_ + i];
  __syncthreads();
  const int e = blockIdx.x * 64 + tid;
  if (e >= E_) return;
  const int myd = dsts[e];
  int rank = 0;
#pragma unroll 4
  for (int k = 0; k < e; ++k) rank += (dsts[k] == myd) ? 1 : 0;
  csr_src[csr_off[myd] + rank] = ei[e];  // src id, stable original-edge order
}

// ---------------- K0c: w_sd[0..63] = W^T att_src, w_sd[64..127] = W^T att_dst ----------------
__global__ __launch_bounds__(128) void k_prep(const float* __restrict__ W,
                                              const float* __restrict__ att_src,
                                              const float* __restrict__ att_dst,
                                              float* __restrict__ w_sd) {
  const int k = threadIdx.x & 63;
  const float* av = (threadIdx.x < 64) ? att_src : att_dst;
  float s = 0.f;
  for (int h = 0; h < H_; ++h) s += W[h * F_ + k] * av[h];
  w_sd[threadIdx.x] = s;
}

__device__ __forceinline__ float bflo(unsigned u) { return __uint_as_float(u << 16); }
__device__ __forceinline__ float bfhi(unsigned u) { return __uint_as_float(u & 0xffff0000u); }

__device__ __forceinline__ unsigned short f2bf(float f) {
  __hip_bfloat16 h = __float2bfloat16(f);
  return *(unsigned short*)&h;
}

__device__ __forceinline__ short8 pack8(float4 u, float4 w) {
  short8 r;
  r[0] = (short)f2bf(u.x); r[1] = (short)f2bf(u.y);
  r[2] = (short)f2bf(u.z); r[3] = (short)f2bf(u.w);
  r[4] = (short)f2bf(w.x); r[5] = (short)f2bf(w.y);
  r[6] = (short)f2bf(w.z); r[7] = (short)f2bf(w.w);
  return r;
}

__device__ __forceinline__ short8 ld8_bf16(const float* p) {
  return pack8(*(const float4*)p, *(const float4*)(p + 4));
}

// GELU via tanh form (max dev from exact ~3e-3, inside budget)
__device__ __forceinline__ float gelu_f(float v) {
  float t = v * (1.5957691216f + 0.0713550903f * (v * v));
  t = fminf(t, 80.0f);
  float e = __expf(t);
  return v * e * __builtin_amdgcn_rcpf(e + 1.0f);
}

// ---------------- main fused kernel: one block per graph, 3 blocks/CU ----------------
__global__ __launch_bounds__(512, 6) void k_gat2(
    const float* __restrict__ x, const int* __restrict__ csr_off_g,
    const int* __restrict__ csr_src_g, const float* __restrict__ W,
    const float* __restrict__ w_sd, const float* __restrict__ bias,
    float* __restrict__ out) {
  __shared__ unsigned short h_s[N_][H_];        // 41600 B bf16, stride 64
  __shared__ unsigned int pack_s[E_];           // 10400 B: src | bf16(alpha_norm)<<16
  __shared__ unsigned int asad_s[N_];           //  1300 B: bf16(a_s) | bf16(a_d)<<16
  __shared__ unsigned short coff_s[N_ + 1];     //   652 B        total 53,956 B

  const int g    = blockIdx.x;      // graph id = b*T + t
  const int bb   = g / T_;
  const int tt   = g % T_;
  const int tid  = threadIdx.x;
  const int lane = tid & 63;
  const int wv   = tid >> 6;        // wave 0..7
  const int l15  = lane & 15;
  const int l4   = lane >> 4;       // 0..3

  // stage CSR (src into low 16 bits of pack_s)
  for (int i = tid; i < E_; i += BLK) pack_s[i] = (unsigned)csr_src_g[i];
  for (int i = tid; i <= N_; i += BLK) coff_s[i] = (unsigned short)csr_off_g[i];

  // B fragments: B[k][c] = W[c][k]; lane holds col ct*16+l15, k = k0*32 + l4*8 + j
  short8 bf[2][4];
#pragma unroll
  for (int ct = 0; ct < 4; ++ct)
#pragma unroll
    for (int k0 = 0; k0 < 2; ++k0)
      bf[k0][ct] = ld8_bf16(W + (size_t)(ct * 16 + l15) * F_ + k0 * 32 + l4 * 8);

  // w fragment: col 0 = w_s, col 1 = w_d, cols 2..15 zero
  short8 bw[2];
  {
    const float* wp = w_sd + (l15 & 1) * 64;
#pragma unroll
    for (int k0 = 0; k0 < 2; ++k0) {
      short8 z = {0, 0, 0, 0, 0, 0, 0, 0};
      bw[k0] = (l15 < 2) ? ld8_bf16(wp + k0 * 32 + l4 * 8) : z;
    }
  }

  // ---------- Phase 1: h = x @ W^T (MFMA) + a_s/a_d (MFMA with [w_s w_d]) ----------
  const float* xg = x + ((size_t)bb * N_ * T_ + tt) * F_;
  for (int t = wv; t < 21; t += 8) {
    const int r0 = t * 16;
    int rr = r0 + l15; if (rr > N_ - 1) rr = N_ - 1;   // clamp partial tile
    const float* xr = xg + (size_t)rr * (T_ * F_);
    const float4 u0 = *(const float4*)(xr + l4 * 8);
    const float4 u1 = *(const float4*)(xr + l4 * 8 + 4);
    const float4 u2 = *(const float4*)(xr + 32 + l4 * 8);
    const float4 u3 = *(const float4*)(xr + 32 + l4 * 8 + 4);
    const short8 a0 = pack8(u0, u1);   // k 0..31
    const short8 a1 = pack8(u2, u3);   // k 32..63

#pragma unroll
    for (int ct = 0; ct < 4; ++ct) {
      f32x4 acc = {0.f, 0.f, 0.f, 0.f};
      acc = __builtin_amdgcn_mfma_f32_16x16x32_bf16(a0, bf[0][ct], acc, 0, 0, 0);
      acc = __builtin_amdgcn_mfma_f32_16x16x32_bf16(a1, bf[1][ct], acc, 0, 0, 0);
      const int col = ct * 16 + l15;                    // C: col = lane&15
#pragma unroll
      for (int j = 0; j < 4; ++j) {                     // C: row = (lane>>4)*4 + j
        const int row = r0 + l4 * 4 + j;
        if (row < N_) h_s[row][col] = f2bf(acc[j]);
      }
    }
    // attention logits: col 0 = a_s, col 1 = a_d
    f32x4 acc2 = {0.f, 0.f, 0.f, 0.f};
    acc2 = __builtin_amdgcn_mfma_f32_16x16x32_bf16(a0, bw[0], acc2, 0, 0, 0);
    acc2 = __builtin_amdgcn_mfma_f32_16x16x32_bf16(a1, bw[1], acc2, 0, 0, 0);
    if (l15 < 2) {
#pragma unroll
      for (int j = 0; j < 4; ++j) {
        const int row = r0 + l4 * 4 + j;
        if (row < N_)
          ((unsigned short*)asad_s)[row * 2 + l15] = f2bf(acc2[j]);  // lo=a_s, hi=a_d
      }
    }
  }
  __syncthreads();

  // ---------- Phase 2: per-dst segment softmax, normalized alpha -> pack high bits ----------
  if (tid < N_) {
    const int n = tid;
    const int beg = coff_s[n], end = coff_s[n + 1];
    const float adn = bfhi(asad_s[n]);
    float mx = -1e30f;
    for (int p = beg; p < end; ++p) {
      const unsigned sp = pack_s[p] & 0xffffu;
      float e = bflo(asad_s[sp]) + adn;
      e = fmaxf(e, 0.2f * e);                 // leaky_relu
      mx = fmaxf(mx, e);
    }
    float den = 0.f;
    for (int p = beg; p < end; ++p) {
      const unsigned sp = pack_s[p] & 0xffffu;
      float e = bflo(asad_s[sp]) + adn;
      e = fmaxf(e, 0.2f * e);
      den += __expf(e - mx);
    }
    const float inv = 1.0f / den;             // unused if segment empty
    for (int p = beg; p < end; ++p) {
      const unsigned sp = pack_s[p] & 0xffffu;
      float e = bflo(asad_s[sp]) + adn;
      e = fmaxf(e, 0.2f * e);
      const float al = __expf(e - mx) * inv;  // normalized alpha
      pack_s[p] = sp | ((unsigned)f2bf(al) << 16);
    }
  }
  __syncthreads();

  // ---------- Phase 3: aggregation + GELU (quarter-wave per dst, 4 ch/lane) ----------
  const int l16 = tid & 15;
  const int qw  = tid >> 4;                   // quarter-wave id 0..31
  const float4 bias4 = *(const float4*)(bias + 4 * l16);
  for (int n = qw; n < N_; n += 32) {
    const int beg = coff_s[n], end = coff_s[n + 1];
    float c0 = 0.f, c1 = 0.f, c2 = 0.f, c3 = 0.f;
    for (int p = beg; p < end; ++p) {
      const unsigned u = pack_s[p];           // broadcast within quarter
      const unsigned s = u & 0xffffu;
      const float   al = bfhi(u);             // normalized alpha
      const uint2 hv = *(const uint2*)(&h_s[s][0] + 4 * l16);  // ds_read_b64
      c0 += al * bflo(hv.x); c1 += al * bfhi(hv.x);
      c2 += al * bflo(hv.y); c3 += al * bfhi(hv.y);
    }
    const float v0 = gelu_f(c0 + bias4.x);
    const float v1 = gelu_f(c1 + bias4.y);
    const float v2 = gelu_f(c2 + bias4.z);
    const float v3 = gelu_f(c3 + bias4.w);
    *(float4*)&out[((size_t)g * N_ + n) * H_ + 4 * l16] =
        make_float4(v0, v1, v2, v3);          // 16 lanes -> 256B contiguous
  }
}

extern "C" void kernel_launch(void* const* d_in, const int* in_sizes, int n_in,
                              void* d_out, int out_size, void* d_ws, size_t ws_size,
                              hipStream_t stream) {
  (void)in_sizes; (void)n_in; (void)out_size; (void)ws_size;
  const float* x       = (const float*)d_in[0];
  const int*   ei      = (const int*)d_in[1];
  const float* W       = (const float*)d_in[2];
  const float* att_src = (const float*)d_in[3];
  const float* att_dst = (const float*)d_in[4];
  const float* bias    = (const float*)d_in[5];
  float* out = (float*)d_out;

  char* ws = (char*)d_ws;
  int*   csr_off = (int*)ws;                          // 326 ints
  int*   csr_src = csr_off + (N_ + 1);                // 2600 ints
  float* w_sd    = (float*)(csr_src + E_);            // 128 floats

  k_offsets<<<1, BLK, 0, stream>>>(ei, csr_off);
  k_scatter<<<(E_ + 63) / 64, 64, 0, stream>>>(ei, csr_off, csr_src);
  k_prep<<<1, 128, 0, stream>>>(W, att_src, att_dst, w_sd);
  k_gat2<<<G_, BLK, 0, stream>>>(x, csr_off, csr_src, W, w_sd, bias, out);
}

// Round 8
// 150.401 us; speedup vs baseline: 1.6940x; 1.0157x over previous
//
#include <hip/hip_runtime.h>
#include <hip/hip_bf16.h>

#define B_  64
#define N_  325
#define T_  24
#define F_  64
#define H_  64
#define E_  2600
#define G_  (B_ * T_)
#define BLK 512
#define GRID2 768   // 2 graphs per block

using half2_t = __attribute__((ext_vector_type(2))) _Float16;
using half8_t = __attribute__((ext_vector_type(8))) _Float16;
using f32x4   = __attribute__((ext_vector_type(4))) float;

// ---------------- K0a: counts -> offsets + degree-sorted perm ----------------
__global__ __launch_bounds__(512) void k_offsets(const int* __restrict__ ei,
                                                 int* __restrict__ csr_off,
                                                 int* __restrict__ perm) {
  __shared__ int cnt[N_];
  const int tid = threadIdx.x;
  for (int i = tid; i < N_; i += BLK) cnt[i] = 0;
  __syncthreads();
  for (int e = tid; e < E_; e += BLK) atomicAdd(&cnt[ei[E_ + e]], 1);
  __syncthreads();
  if (tid <= N_) {
    int off = 0;
    for (int m = 0; m < N_; ++m) off += (m < tid) ? cnt[m] : 0;  // uniform m -> LDS broadcast
    csr_off[tid] = off;
  }
  if (tid < N_) {
    const int c = cnt[tid];
    int r = 0;
    for (int m = 0; m < N_; ++m) {
      const int cm = cnt[m];                 // uniform -> broadcast
      r += (cm > c || (cm == c && m < tid)) ? 1 : 0;
    }
    perm[r] = tid;                           // descending degree, stable
  }
}

// ---------------- K0b: stable scatter of src ids by dst ----------------
__global__ __launch_bounds__(64) void k_scatter(const int* __restrict__ ei,
                                                const int* __restrict__ csr_off,
                                                int* __restrict__ csr_src) {
  __shared__ int dsts[E_];
  const int tid = threadIdx.x;
  for (int i = tid; i < E_; i += 64) dsts[i] = ei[E_ + i];
  __syncthreads();
  const int e = blockIdx.x * 64 + tid;
  if (e >= E_) return;
  const int myd = dsts[e];
  int rank = 0;
#pragma unroll 4
  for (int k = 0; k < e; ++k) rank += (dsts[k] == myd) ? 1 : 0;
  csr_src[csr_off[myd] + rank] = ei[e];
}

// ---------------- K0c: w_sd[0..63] = W^T att_src, [64..127] = W^T att_dst ----------------
__global__ __launch_bounds__(128) void k_prep(const float* __restrict__ W,
                                              const float* __restrict__ att_src,
                                              const float* __restrict__ att_dst,
                                              float* __restrict__ w_sd) {
  const int k = threadIdx.x & 63;
  const float* av = (threadIdx.x < 64) ? att_src : att_dst;
  float s = 0.f;
  for (int h = 0; h < H_; ++h) s += W[h * F_ + k] * av[h];
  w_sd[threadIdx.x] = s;
}

__device__ __forceinline__ float f16lo(unsigned u) {
  half2_t h = __builtin_bit_cast(half2_t, u); return (float)h[0];
}
__device__ __forceinline__ float f16hi(unsigned u) {
  half2_t h = __builtin_bit_cast(half2_t, u); return (float)h[1];
}
__device__ __forceinline__ unsigned short f16b(float f) {
  _Float16 h = (_Float16)f; return __builtin_bit_cast(unsigned short, h);
}
__device__ __forceinline__ float f16u(unsigned short u) {
  return (float)__builtin_bit_cast(_Float16, u);
}

__device__ __forceinline__ half2_t pkrtz(float a, float b) {
  return __builtin_bit_cast(half2_t, __builtin_amdgcn_cvt_pkrtz(a, b));
}

__device__ __forceinline__ half8_t pk8(float4 a, float4 b) {
  half2_t p0 = pkrtz(a.x, a.y);
  half2_t p1 = pkrtz(a.z, a.w);
  half2_t p2 = pkrtz(b.x, b.y);
  half2_t p3 = pkrtz(b.z, b.w);
  half8_t r;
  r[0] = p0[0]; r[1] = p0[1]; r[2] = p1[0]; r[3] = p1[1];
  r[4] = p2[0]; r[5] = p2[1]; r[6] = p3[0]; r[7] = p3[1];
  return r;
}
__device__ __forceinline__ half8_t ld8f16(const float* p) {
  return pk8(*(const float4*)p, *(const float4*)(p + 4));
}

// GELU via tanh form (max dev ~3e-3)
__device__ __forceinline__ float gelu_f(float v) {
  float t = v * (1.5957691216f + 0.0713550903f * (v * v));
  t = fminf(t, 80.0f);
  float e = __expf(t);
  return v * e * __builtin_amdgcn_rcpf(e + 1.0f);
}

// ---------------- main fused kernel: 2 graphs per block, 3 blocks/CU ----------------
__global__ __launch_bounds__(512, 6) void k_gat2(
    const float* __restrict__ x, const int* __restrict__ csr_off_g,
    const int* __restrict__ csr_src_g, const int* __restrict__ perm_g,
    const float* __restrict__ W, const float* __restrict__ w_sd,
    const float* __restrict__ bias, float* __restrict__ out) {
  __shared__ _Float16 h_s[N_][H_];          // 41600 B
  __shared__ unsigned pack_s[E_];           // 10400 B: src | f16(e/alpha)<<16
  __shared__ unsigned asad_s[N_];           //  1300 B: f16 a_s | f16 a_d<<16
  __shared__ unsigned short den_s[N_];      //   652 B: f16 (1/den)   total 53,952 B

  const int tid  = threadIdx.x;
  const int lane = tid & 63;
  const int wv   = tid >> 6;
  const int l15  = lane & 15;
  const int l4   = lane >> 4;

  // stage src ids once (low 16 bits survive both graphs)
  for (int i = tid; i < E_; i += BLK) pack_s[i] = (unsigned)csr_src_g[i];

  // W fragments (f16): B[k][c] = W[c][k]; lane: col ct*16+l15, k = k0*32 + l4*8 + j
  half8_t bf[2][4];
#pragma unroll
  for (int ct = 0; ct < 4; ++ct)
#pragma unroll
    for (int k0 = 0; k0 < 2; ++k0)
      bf[k0][ct] = ld8f16(W + (size_t)(ct * 16 + l15) * F_ + k0 * 32 + l4 * 8);

  // attention-vector fragment: col 0 = w_s, col 1 = w_d
  half8_t bw[2];
  {
    const float* wp = w_sd + (l15 & 1) * 64;
#pragma unroll
    for (int k0 = 0; k0 < 2; ++k0) {
      half8_t z = {0, 0, 0, 0, 0, 0, 0, 0};
      bw[k0] = (l15 < 2) ? ld8f16(wp + k0 * 32 + l4 * 8) : z;
    }
  }

  const int l16v = tid & 15;
  const int qw   = tid >> 4;                 // quarter-wave 0..31
  const float4 bias4 = *(const float4*)(bias + 4 * l16v);

  for (int gi = 0; gi < 2; ++gi) {
    const int g  = blockIdx.x + gi * GRID2;  // graph id = b*T + t
    const int bb = g / T_;
    const int tt = g % T_;
    if (gi) __syncthreads();                 // prev graph's phase 3 done

    // ---------- Phase 1: h = x @ W^T + [a_s a_d] via MFMA f16 ----------
    const float* xg = x + ((size_t)bb * N_ * T_ + tt) * F_;
    for (int t = wv; t < 21; t += 8) {
      const int r0 = t * 16;
      int rr = r0 + l15; if (rr > N_ - 1) rr = N_ - 1;
      const float* xr = xg + (size_t)rr * (T_ * F_);
      const float4 u0 = *(const float4*)(xr + l4 * 8);
      const float4 u1 = *(const float4*)(xr + l4 * 8 + 4);
      const float4 u2 = *(const float4*)(xr + 32 + l4 * 8);
      const float4 u3 = *(const float4*)(xr + 32 + l4 * 8 + 4);
      const half8_t a0 = pk8(u0, u1);        // k 0..31
      const half8_t a1 = pk8(u2, u3);        // k 32..63
      const bool full = (r0 + 16 <= N_);

#pragma unroll
      for (int ct = 0; ct < 4; ++ct) {
        f32x4 acc = {0.f, 0.f, 0.f, 0.f};
        acc = __builtin_amdgcn_mfma_f32_16x16x32_f16(a0, bf[0][ct], acc, 0, 0, 0);
        acc = __builtin_amdgcn_mfma_f32_16x16x32_f16(a1, bf[1][ct], acc, 0, 0, 0);
        const int col = ct * 16 + l15;       // C: col = lane&15
#pragma unroll
        for (int j = 0; j < 4; ++j) {        // C: row = (lane>>4)*4 + j
          const int row = r0 + l4 * 4 + j;
          if (full || row < N_) h_s[row][col] = (_Float16)acc[j];
        }
      }
      f32x4 acc2 = {0.f, 0.f, 0.f, 0.f};
      acc2 = __builtin_amdgcn_mfma_f32_16x16x32_f16(a0, bw[0], acc2, 0, 0, 0);
      acc2 = __builtin_amdgcn_mfma_f32_16x16x32_f16(a1, bw[1], acc2, 0, 0, 0);
      if (l15 < 2) {
#pragma unroll
        for (int j = 0; j < 4; ++j) {
          const int row = r0 + l4 * 4 + j;
          if (full || row < N_)
            ((unsigned short*)asad_s)[row * 2 + l15] = f16b(acc2[j]);
        }
      }
    }
    __syncthreads();

    // ---------- Phase 2: segment softmax (thread per dst, degree-sorted, 2 passes) ----------
    if (tid < N_) {
      const int n   = perm_g[tid];
      const int beg = csr_off_g[n], end = csr_off_g[n + 1];
      const float adn = f16hi(asad_s[n]);
      float mx = -1e30f;
      for (int p = beg; p < end; ++p) {
        const unsigned sp = pack_s[p] & 0xffffu;
        float e = f16lo(asad_s[sp]) + adn;
        e = fmaxf(e, 0.2f * e);              // leaky_relu
        pack_s[p] = sp | ((unsigned)f16b(e) << 16);
        mx = fmaxf(mx, e);
      }
      float den = 0.f;
      for (int p = beg; p < end; ++p) {
        const unsigned u = pack_s[p];
        const float ex = __expf(f16hi(u) - mx);
        den += ex;
        pack_s[p] = (u & 0xffffu) | ((unsigned)f16b(ex) << 16);
      }
      den_s[n] = f16b((end > beg) ? (1.0f / den) : 1.0f);
    }
    __syncthreads();

    // ---------- Phase 3: aggregation (pk_fma_f16) + scale + GELU ----------
    for (int idx = qw; idx < N_; idx += 32) {
      const int n   = perm_g[idx];           // uniform within quarter
      const int beg = csr_off_g[n], end = csr_off_g[n + 1];
      half2_t a01 = {(_Float16)0.f, (_Float16)0.f};
      half2_t a23 = {(_Float16)0.f, (_Float16)0.f};
      for (int p = beg; p < end; ++p) {
        const unsigned u  = pack_s[p];       // broadcast within quarter
        const unsigned s  = u & 0xffffu;
        const unsigned au = u >> 16;
        const half2_t al2 = __builtin_bit_cast(half2_t, au | (au << 16));
        const uint2 hv = *(const uint2*)&h_s[s][4 * l16v];   // ds_read_b64
        a01 = al2 * __builtin_bit_cast(half2_t, hv.x) + a01; // v_pk_fma_f16
        a23 = al2 * __builtin_bit_cast(half2_t, hv.y) + a23;
      }
      const float inv = f16u(den_s[n]);
      const float v0 = gelu_f((float)a01[0] * inv + bias4.x);
      const float v1 = gelu_f((float)a01[1] * inv + bias4.y);
      const float v2 = gelu_f((float)a23[0] * inv + bias4.z);
      const float v3 = gelu_f((float)a23[1] * inv + bias4.w);
      *(float4*)&out[((size_t)g * N_ + n) * H_ + 4 * l16v] =
          make_float4(v0, v1, v2, v3);       // 16 lanes -> 256B contiguous
    }
  }
}

extern "C" void kernel_launch(void* const* d_in, const int* in_sizes, int n_in,
                              void* d_out, int out_size, void* d_ws, size_t ws_size,
                              hipStream_t stream) {
  (void)in_sizes; (void)n_in; (void)out_size; (void)ws_size;
  const float* x       = (const float*)d_in[0];
  const int*   ei      = (const int*)d_in[1];
  const float* W       = (const float*)d_in[2];
  const float* att_src = (const float*)d_in[3];
  const float* att_dst = (const float*)d_in[4];
  const float* bias    = (const float*)d_in[5];
  float* out = (float*)d_out;

  char* ws = (char*)d_ws;
  int*   csr_off = (int*)ws;                      // N_+1 ints
  int*   csr_src = csr_off + (N_ + 1);            // E_ ints
  int*   perm    = csr_src + E_;                  // N_ ints
  float* w_sd    = (float*)(perm + N_);           // 128 floats

  k_offsets<<<1, BLK, 0, stream>>>(ei, csr_off, perm);
  k_scatter<<<(E_ + 63) / 64, 64, 0, stream>>>(ei, csr_off, csr_src);
  k_prep<<<1, 128, 0, stream>>>(W, att_src, att_dst, w_sd);
  k_gat2<<<GRID2, BLK, 0, stream>>>(x, csr_off, csr_src, perm, W, w_sd, bias, out);
}